// Round 1
// baseline (385.370 us; speedup 1.0000x reference)
//
#include <hip/hip_runtime.h>
#include <hip/hip_bf16.h>

#define HWD 128
#define NCH 64
#define NK  9

typedef __attribute__((ext_vector_type(8))) short s16x8;
typedef __attribute__((ext_vector_type(4))) float f32x4;

__device__ __forceinline__ float bf2f(short s) {
  union { unsigned u; float f; } cv;
  cv.u = ((unsigned)(unsigned short)s) << 16;
  return cv.f;
}
__device__ __forceinline__ short f2bf(float f) {
  union { float f; unsigned u; } cv; cv.f = f;
  unsigned r = cv.u + 0x7fffu + ((cv.u >> 16) & 1u);
  return (short)(r >> 16);
}

// ---- w_def [64 o][64 c][3][3] f32  ->  wbt [9 k][64 o][64 c] bf16 (B^T layout) ----
__global__ void prep_w_kernel(const float* __restrict__ wd, short* __restrict__ wbt) {
  int i = blockIdx.x * 256 + threadIdx.x;
  if (i >= NK * 64 * 64) return;
  int c = i & 63;
  int o = (i >> 6) & 63;
  int k = i >> 12;
  wbt[i] = f2bf(wd[(o * 64 + c) * 9 + k]);
}

// ---- x NCHW f32 -> xt NHWC bf16 ----
__global__ __launch_bounds__(256) void transpose_x_kernel(const float* __restrict__ x,
                                                          short* __restrict__ xt) {
  __shared__ float tile[64][129];
  int bid = blockIdx.x;
  int b = bid >> 7, h = bid & 127;
  int t = threadIdx.x;
  const float* xb = x + ((size_t)b * NCH) * HWD * HWD + (size_t)h * HWD;
  #pragma unroll 4
  for (int i = 0; i < 32; ++i) {
    int c = (t >> 7) + 2 * i;
    int w = t & 127;
    tile[c][w] = xb[(size_t)c * HWD * HWD + w];
  }
  __syncthreads();
  short* xto = xt + (((size_t)b * HWD + h) * HWD) * NCH;
  #pragma unroll 4
  for (int i = 0; i < 32; ++i) {
    int idx = i * 256 + t;
    int c = idx & 63, w = idx >> 6;
    xto[(size_t)w * NCH + c] = f2bf(tile[c][w]);
  }
}

// ---- offset conv: direct fp32 3x3 conv, C=64 -> 18, pad 1, + bias ----
__global__ __launch_bounds__(128) void off_conv_kernel(const float* __restrict__ x,
                                                       const float* __restrict__ wo,
                                                       const float* __restrict__ bo,
                                                       float* __restrict__ off) {
  int bid = blockIdx.x;               // (b*18 + j)*128 + h
  int h = bid & 127;
  int j = (bid >> 7) % 18;
  int b = bid / (18 * 128);
  int w = threadIdx.x;
  float acc = bo[j];
  const float* wp = wo + j * 576;     // [c][ky][kx]
  const float* xb = x + (size_t)b * NCH * HWD * HWD;
  for (int c = 0; c < NCH; ++c) {
    #pragma unroll
    for (int dy = 0; dy < 3; ++dy) {
      int y = h + dy - 1;
      if (y < 0 || y >= HWD) continue;
      const float* row = xb + ((size_t)c * HWD + y) * HWD;
      #pragma unroll
      for (int dx = 0; dx < 3; ++dx) {
        int xx = w + dx - 1;
        float v = (xx >= 0 && xx < HWD) ? row[xx] : 0.f;
        acc += v * wp[c * 9 + dy * 3 + dx];
      }
    }
  }
  off[(((size_t)b * 18 + j) * HWD + h) * HWD + w] = acc;
}

// ---- main deformable conv: gather -> LDS bf16 -> MFMA GEMM (M=64 px, N=64 oc, K=576) ----
__global__ __launch_bounds__(256) void deform_main_kernel(
    const float* __restrict__ off, const short* __restrict__ xt,
    const short* __restrict__ wbt, float* __restrict__ out)
{
  __shared__ char smem_raw[64 * 65 * 4];       // 16640 B; taps: val[64][72] bf16 (9216 B)
  short* vlds = (short*)smem_raw;

  int bid = blockIdx.x;
  int wseg = bid & 1;
  int h = (bid >> 1) & 127;
  int b = bid >> 8;
  int w0 = wseg * 64;

  int t = threadIdx.x;
  int lane = t & 63;
  int wv = t >> 6;
  int p = t >> 2;       // pixel 0..63 in tile
  int q = t & 3;        // channel quarter
  int w = w0 + p;

  f32x4 acc[4];
  #pragma unroll
  for (int nt = 0; nt < 4; ++nt) acc[nt] = (f32x4){0.f, 0.f, 0.f, 0.f};

  int arow = wv * 16 + (lane & 15);
  int acol_half = (lane >> 4) * 8;

  const size_t off_b = (size_t)b * 18 * HWD * HWD + (size_t)h * HWD + w;
  const short* xtb = xt + ((size_t)b * HWD * HWD) * NCH;

  for (int k = 0; k < NK; ++k) {
    // B fragments from global (L2-hot, [k][o][c] with c contiguous)
    s16x8 bfr[4][2];
    #pragma unroll
    for (int nt = 0; nt < 4; ++nt) {
      #pragma unroll
      for (int s = 0; s < 2; ++s) {
        int o = nt * 16 + (lane & 15);
        int c = s * 32 + acol_half;
        bfr[nt][s] = *(const s16x8*)(wbt + ((k * 64 + o) * 64 + c));
      }
    }

    // ---- gather phase ----
    float offy = off[off_b + (size_t)(2 * k) * HWD * HWD];
    float offx = off[off_b + (size_t)(2 * k + 1) * HWD * HWD];
    int ky = k / 3, kx = k - ky * 3;
    float py = offy + (float)(h - 1 + ky);
    float px = offx + (float)(w - 1 + kx);
    float y0f = floorf(py), x0f = floorf(px);
    float wy1 = py - y0f, wx1 = px - x0f;
    float wy0 = 1.f - wy1, wx0 = 1.f - wx1;
    int y0 = (int)y0f, x0 = (int)x0f;

    float v[16];
    #pragma unroll
    for (int j = 0; j < 16; ++j) v[j] = 0.f;

    #pragma unroll
    for (int cy = 0; cy < 2; ++cy) {
      #pragma unroll
      for (int cx = 0; cx < 2; ++cx) {
        int yy = y0 + cy, xx = x0 + cx;
        float wt = (cy ? wy1 : wy0) * (cx ? wx1 : wx0);
        bool ok = (yy >= 0) & (yy < HWD) & (xx >= 0) & (xx < HWD);
        float wz = ok ? wt : 0.f;
        int yc = min(max(yy, 0), HWD - 1);
        int xc = min(max(xx, 0), HWD - 1);
        const short* src = xtb + (size_t)(yc * HWD + xc) * NCH + q * 16;
        s16x8 r0 = *(const s16x8*)(src);
        s16x8 r1 = *(const s16x8*)(src + 8);
        #pragma unroll
        for (int j = 0; j < 8; ++j) {
          v[j]     += wz * bf2f(r0[j]);
          v[8 + j] += wz * bf2f(r1[j]);
        }
      }
    }

    s16x8 pk0, pk1;
    #pragma unroll
    for (int j = 0; j < 8; ++j) { pk0[j] = f2bf(v[j]); pk1[j] = f2bf(v[8 + j]); }

    __syncthreads();   // previous tap's A-fragment reads complete
    *(s16x8*)(vlds + p * 72 + q * 16)     = pk0;
    *(s16x8*)(vlds + p * 72 + q * 16 + 8) = pk1;
    __syncthreads();

    // ---- MFMA phase ----
    s16x8 afr[2];
    #pragma unroll
    for (int s = 0; s < 2; ++s)
      afr[s] = *(const s16x8*)(vlds + arow * 72 + s * 32 + acol_half);
    #pragma unroll
    for (int nt = 0; nt < 4; ++nt) {
      #pragma unroll
      for (int s = 0; s < 2; ++s)
        acc[nt] = __builtin_amdgcn_mfma_f32_16x16x32_bf16(afr[s], bfr[nt][s], acc[nt], 0, 0, 0);
    }
  }

  // ---- epilogue: stage through LDS for coalesced NCHW stores ----
  __syncthreads();
  float* ost = (float*)smem_raw;  // [64 oc][65]
  #pragma unroll
  for (int nt = 0; nt < 4; ++nt) {
    int oc = nt * 16 + (lane & 15);
    int pr = wv * 16 + (lane >> 4) * 4;
    #pragma unroll
    for (int r = 0; r < 4; ++r)
      ost[oc * 65 + pr + r] = acc[nt][r];
  }
  __syncthreads();
  float* ob = out + ((size_t)(b * NCH) * HWD + h) * HWD + w0;
  #pragma unroll
  for (int i = 0; i < 16; ++i) {
    int idx = i * 256 + t;
    int px = idx & 63, oc = idx >> 6;
    ob[(size_t)oc * HWD * HWD + px] = ost[oc * 65 + px];
  }
}

extern "C" void kernel_launch(void* const* d_in, const int* in_sizes, int n_in,
                              void* d_out, int out_size, void* d_ws, size_t ws_size,
                              hipStream_t stream) {
  const float* x     = (const float*)d_in[0];
  const float* w_off = (const float*)d_in[1];
  const float* b_off = (const float*)d_in[2];
  const float* w_def = (const float*)d_in[3];
  float* out = (float*)d_out;

  char* ws = (char*)d_ws;
  float* off_ws = (float*)ws;                          // 8*18*128*128*4 = 9,437,184 B
  short* xt     = (short*)(ws + 9437184);              // 8*128*128*64*2 = 16,777,216 B
  short* wbt    = (short*)(ws + 9437184 + 16777216);   // 9*64*64*2      =     73,728 B

  hipLaunchKernelGGL(prep_w_kernel,      dim3(144),        dim3(256), 0, stream, w_def, wbt);
  hipLaunchKernelGGL(transpose_x_kernel, dim3(1024),       dim3(256), 0, stream, x, xt);
  hipLaunchKernelGGL(off_conv_kernel,    dim3(8*18*128),   dim3(128), 0, stream, x, w_off, b_off, off_ws);
  hipLaunchKernelGGL(deform_main_kernel, dim3(2048),       dim3(256), 0, stream, off_ws, xt, wbt, out);
}

// Round 2
// 159.974 us; speedup vs baseline: 2.4090x; 2.4090x over previous
//
#include <hip/hip_runtime.h>
#include <hip/hip_bf16.h>

#define HWD 128
#define NCH 64
#define NK  9

typedef __attribute__((ext_vector_type(8))) short s16x8;
typedef __attribute__((ext_vector_type(4))) float f32x4;

__device__ __forceinline__ float bf2f(short s) {
  union { unsigned u; float f; } cv;
  cv.u = ((unsigned)(unsigned short)s) << 16;
  return cv.f;
}
__device__ __forceinline__ short f2bf(float f) {
  union { float f; unsigned u; } cv; cv.f = f;
  unsigned r = cv.u + 0x7fffu + ((cv.u >> 16) & 1u);
  return (short)(r >> 16);
}

// ---- w_def [64 o][64 c][3][3] f32  ->  wbt [9 k][64 o][64 c] bf16 (B^T layout) ----
__global__ void prep_w_kernel(const float* __restrict__ wd, short* __restrict__ wbt) {
  int i = blockIdx.x * 256 + threadIdx.x;
  if (i >= NK * 64 * 64) return;
  int c = i & 63;
  int o = (i >> 6) & 63;
  int k = i >> 12;
  wbt[i] = f2bf(wd[(o * 64 + c) * 9 + k]);
}

// ---- w_off [18 o][64 c][3][3] f32 -> wbo [9 k][32 o_pad][64 c] bf16 ----
__global__ void prep_wo_kernel(const float* __restrict__ wo, short* __restrict__ wbo) {
  int i = blockIdx.x * 256 + threadIdx.x;
  if (i >= NK * 32 * 64) return;
  int c = i & 63;
  int o = (i >> 6) & 31;
  int k = i >> 11;
  wbo[i] = (o < 18) ? f2bf(wo[(o * 64 + c) * 9 + k]) : (short)0;
}

// ---- x NCHW f32 -> xt NHWC bf16 ----
__global__ __launch_bounds__(256) void transpose_x_kernel(const float* __restrict__ x,
                                                          short* __restrict__ xt) {
  __shared__ float tile[64][129];
  int bid = blockIdx.x;
  int b = bid >> 7, h = bid & 127;
  int t = threadIdx.x;
  const float* xb = x + ((size_t)b * NCH) * HWD * HWD + (size_t)h * HWD;
  #pragma unroll 4
  for (int i = 0; i < 32; ++i) {
    int c = (t >> 7) + 2 * i;
    int w = t & 127;
    tile[c][w] = xb[(size_t)c * HWD * HWD + w];
  }
  __syncthreads();
  short* xto = xt + (((size_t)b * HWD + h) * HWD) * NCH;
  #pragma unroll 4
  for (int i = 0; i < 32; ++i) {
    int idx = i * 256 + t;
    int c = idx & 63, w = idx >> 6;
    xto[(size_t)w * NCH + c] = f2bf(tile[c][w]);
  }
}

// ---- offset conv via MFMA: off[b,18,h,w] = GEMM(M=pixels, N=32pad, K=576) + bias ----
// A fragments load DIRECTLY from xt (static 3x3 shifts, L1/L2-hot). No LDS.
__global__ __launch_bounds__(256) void off_conv_mfma_kernel(
    const short* __restrict__ xt, const short* __restrict__ wbo,
    const float* __restrict__ bo, float* __restrict__ off)
{
  int bid = blockIdx.x;
  int wseg = bid & 1;
  int h = (bid >> 1) & 127;
  int b = bid >> 8;
  int w0 = wseg * 64;

  int t = threadIdx.x;
  int lane = t & 63;
  int wv = t >> 6;

  int arow = wv * 16 + (lane & 15);      // pixel row of A fragment (0..63)
  int ahalf = (lane >> 4) * 8;           // K sub-offset within 32-block

  f32x4 acc[2];
  acc[0] = (f32x4){0.f, 0.f, 0.f, 0.f};
  acc[1] = (f32x4){0.f, 0.f, 0.f, 0.f};

  const short* xtb = xt + ((size_t)b * HWD * HWD) * NCH;
  const s16x8 zv = (s16x8){0,0,0,0,0,0,0,0};

  for (int k = 0; k < NK; ++k) {
    int ky = k / 3, kx = k - ky * 3;
    int y = h - 1 + ky;
    int xx = w0 + arow - 1 + kx;
    bool ok = (y >= 0) & (y < HWD) & (xx >= 0) & (xx < HWD);
    int yc = min(max(y, 0), HWD - 1);
    int xc = min(max(xx, 0), HWD - 1);
    const short* asrc = xtb + (size_t)(yc * HWD + xc) * NCH + ahalf;

    s16x8 afr[2];
    #pragma unroll
    for (int s = 0; s < 2; ++s) {
      s16x8 a = *(const s16x8*)(asrc + s * 32);
      afr[s] = ok ? a : zv;
    }

    #pragma unroll
    for (int nt = 0; nt < 2; ++nt) {
      int o = nt * 16 + (lane & 15);
      #pragma unroll
      for (int s = 0; s < 2; ++s) {
        s16x8 bfr = *(const s16x8*)(wbo + ((k * 32 + o) * 64 + s * 32 + ahalf));
        acc[nt] = __builtin_amdgcn_mfma_f32_16x16x32_bf16(afr[s], bfr, acc[nt], 0, 0, 0);
      }
    }
  }

  // Epilogue: C layout col=lane&15 (o), row=(lane>>4)*4+r (pixel). 4 consecutive
  // pixels per lane -> contiguous float4 store into off[b][o][h][w].
  int pbase = w0 + wv * 16 + (lane >> 4) * 4;
  #pragma unroll
  for (int nt = 0; nt < 2; ++nt) {
    int o = nt * 16 + (lane & 15);
    if (o < 18) {
      float bias = bo[o];
      f32x4 r = acc[nt];
      r[0] += bias; r[1] += bias; r[2] += bias; r[3] += bias;
      float* dst = off + (((size_t)b * 18 + o) * HWD + h) * HWD + pbase;
      *(f32x4*)dst = r;
    }
  }
}

// ---- main deformable conv: gather -> LDS bf16 -> MFMA GEMM (M=64 px, N=64 oc, K=576) ----
__global__ __launch_bounds__(256) void deform_main_kernel(
    const float* __restrict__ off, const short* __restrict__ xt,
    const short* __restrict__ wbt, float* __restrict__ out)
{
  __shared__ char smem_raw[64 * 65 * 4];       // 16640 B; taps: val[64][72] bf16 (9216 B)
  short* vlds = (short*)smem_raw;

  int bid = blockIdx.x;
  int wseg = bid & 1;
  int h = (bid >> 1) & 127;
  int b = bid >> 8;
  int w0 = wseg * 64;

  int t = threadIdx.x;
  int lane = t & 63;
  int wv = t >> 6;
  int p = t >> 2;       // pixel 0..63 in tile
  int q = t & 3;        // channel quarter
  int w = w0 + p;

  f32x4 acc[4];
  #pragma unroll
  for (int nt = 0; nt < 4; ++nt) acc[nt] = (f32x4){0.f, 0.f, 0.f, 0.f};

  int arow = wv * 16 + (lane & 15);
  int acol_half = (lane >> 4) * 8;

  const size_t off_b = (size_t)b * 18 * HWD * HWD + (size_t)h * HWD + w;
  const short* xtb = xt + ((size_t)b * HWD * HWD) * NCH;

  for (int k = 0; k < NK; ++k) {
    // B fragments from global (L2-hot, [k][o][c] with c contiguous)
    s16x8 bfr[4][2];
    #pragma unroll
    for (int nt = 0; nt < 4; ++nt) {
      #pragma unroll
      for (int s = 0; s < 2; ++s) {
        int o = nt * 16 + (lane & 15);
        int c = s * 32 + acol_half;
        bfr[nt][s] = *(const s16x8*)(wbt + ((k * 64 + o) * 64 + c));
      }
    }

    // ---- gather phase ----
    float offy = off[off_b + (size_t)(2 * k) * HWD * HWD];
    float offx = off[off_b + (size_t)(2 * k + 1) * HWD * HWD];
    int ky = k / 3, kx = k - ky * 3;
    float py = offy + (float)(h - 1 + ky);
    float px = offx + (float)(w - 1 + kx);
    float y0f = floorf(py), x0f = floorf(px);
    float wy1 = py - y0f, wx1 = px - x0f;
    float wy0 = 1.f - wy1, wx0 = 1.f - wx1;
    int y0 = (int)y0f, x0 = (int)x0f;

    float v[16];
    #pragma unroll
    for (int j = 0; j < 16; ++j) v[j] = 0.f;

    #pragma unroll
    for (int cy = 0; cy < 2; ++cy) {
      #pragma unroll
      for (int cx = 0; cx < 2; ++cx) {
        int yy = y0 + cy, xx = x0 + cx;
        float wt = (cy ? wy1 : wy0) * (cx ? wx1 : wx0);
        bool ok = (yy >= 0) & (yy < HWD) & (xx >= 0) & (xx < HWD);
        float wz = ok ? wt : 0.f;
        int yc = min(max(yy, 0), HWD - 1);
        int xc = min(max(xx, 0), HWD - 1);
        const short* src = xtb + (size_t)(yc * HWD + xc) * NCH + q * 16;
        s16x8 r0 = *(const s16x8*)(src);
        s16x8 r1 = *(const s16x8*)(src + 8);
        #pragma unroll
        for (int j = 0; j < 8; ++j) {
          v[j]     += wz * bf2f(r0[j]);
          v[8 + j] += wz * bf2f(r1[j]);
        }
      }
    }

    s16x8 pk0, pk1;
    #pragma unroll
    for (int j = 0; j < 8; ++j) { pk0[j] = f2bf(v[j]); pk1[j] = f2bf(v[8 + j]); }

    __syncthreads();   // previous tap's A-fragment reads complete
    *(s16x8*)(vlds + p * 72 + q * 16)     = pk0;
    *(s16x8*)(vlds + p * 72 + q * 16 + 8) = pk1;
    __syncthreads();

    // ---- MFMA phase ----
    s16x8 afr[2];
    #pragma unroll
    for (int s = 0; s < 2; ++s)
      afr[s] = *(const s16x8*)(vlds + arow * 72 + s * 32 + acol_half);
    #pragma unroll
    for (int nt = 0; nt < 4; ++nt) {
      #pragma unroll
      for (int s = 0; s < 2; ++s)
        acc[nt] = __builtin_amdgcn_mfma_f32_16x16x32_bf16(afr[s], bfr[nt][s], acc[nt], 0, 0, 0);
    }
  }

  // ---- epilogue: stage through LDS for coalesced NCHW stores ----
  __syncthreads();
  float* ost = (float*)smem_raw;  // [64 oc][65]
  #pragma unroll
  for (int nt = 0; nt < 4; ++nt) {
    int oc = nt * 16 + (lane & 15);
    int pr = wv * 16 + (lane >> 4) * 4;
    #pragma unroll
    for (int r = 0; r < 4; ++r)
      ost[oc * 65 + pr + r] = acc[nt][r];
  }
  __syncthreads();
  float* ob = out + ((size_t)(b * NCH) * HWD + h) * HWD + w0;
  #pragma unroll
  for (int i = 0; i < 16; ++i) {
    int idx = i * 256 + t;
    int px = idx & 63, oc = idx >> 6;
    ob[(size_t)oc * HWD * HWD + px] = ost[oc * 65 + px];
  }
}

extern "C" void kernel_launch(void* const* d_in, const int* in_sizes, int n_in,
                              void* d_out, int out_size, void* d_ws, size_t ws_size,
                              hipStream_t stream) {
  const float* x     = (const float*)d_in[0];
  const float* w_off = (const float*)d_in[1];
  const float* b_off = (const float*)d_in[2];
  const float* w_def = (const float*)d_in[3];
  float* out = (float*)d_out;

  char* ws = (char*)d_ws;
  float* off_ws = (float*)ws;                          // 8*18*128*128*4 = 9,437,184 B
  short* xt     = (short*)(ws + 9437184);              // 8*128*128*64*2 = 16,777,216 B
  short* wbt    = (short*)(ws + 9437184 + 16777216);   // 9*64*64*2      =     73,728 B
  short* wbo    = (short*)(ws + 9437184 + 16777216 + 73728); // 9*32*64*2 = 36,864 B

  hipLaunchKernelGGL(prep_w_kernel,       dim3(144),  dim3(256), 0, stream, w_def, wbt);
  hipLaunchKernelGGL(prep_wo_kernel,      dim3(72),   dim3(256), 0, stream, w_off, wbo);
  hipLaunchKernelGGL(transpose_x_kernel,  dim3(1024), dim3(256), 0, stream, x, xt);
  hipLaunchKernelGGL(off_conv_mfma_kernel,dim3(2048), dim3(256), 0, stream, xt, wbo, b_off, off_ws);
  hipLaunchKernelGGL(deform_main_kernel,  dim3(2048), dim3(256), 0, stream, off_ws, xt, wbt, out);
}